// Round 3
// baseline (808.961 us; speedup 1.0000x reference)
//
#include <hip/hip_runtime.h>
#include <stdint.h>

#define D_IN 128
#define D_H  256
#define BM   64
#define NODE_GRID 2048

typedef float f32x4 __attribute__((ext_vector_type(4)));
typedef short s16x8 __attribute__((ext_vector_type(8)));
typedef unsigned int u32x2 __attribute__((ext_vector_type(2)));
typedef unsigned int u32x4 __attribute__((ext_vector_type(4)));

__device__ __forceinline__ unsigned short f2bf(float x) {
  union { float f; uint32_t u; } v; v.f = x;
  uint32_t r = v.u + 0x7fffu + ((v.u >> 16) & 1u);   // RNE
  return (unsigned short)(r >> 16);
}
__device__ __forceinline__ float bf2f(unsigned short u) {
  union { uint32_t u; float f; } v; v.u = (uint32_t)u << 16;
  return v.f;
}

// ---------------- prep: zero pooled accumulator, cast/transpose weights ----------------
__global__ void prep_kernel(const float* __restrict__ W1, const float* __restrict__ W2,
                            const float* __restrict__ Wg1,
                            float* __restrict__ pooled, unsigned short* __restrict__ W1t,
                            unsigned short* __restrict__ W2t, unsigned short* __restrict__ Wg1t,
                            int pooled_n) {
  int stride = gridDim.x * blockDim.x;
  int tid = blockIdx.x * blockDim.x + threadIdx.x;
  float4 z4 = make_float4(0.f, 0.f, 0.f, 0.f);
  for (int i = tid; i < (pooled_n >> 2); i += stride) ((float4*)pooled)[i] = z4;
  for (int i = tid; i < D_H * D_IN; i += stride) {
    int n = i >> 7, k = i & (D_IN - 1);
    W1t[i] = f2bf(W1[k * D_H + n]);
  }
  for (int i = tid; i < D_H * D_H; i += stride) {
    int n = i >> 8, k = i & (D_H - 1);
    W2t[i]  = f2bf(W2[k * D_H + n]);
    Wg1t[i] = f2bf(Wg1[k * D_H + n]);
  }
}

// ---------------- node MLP + fused segment-sum (pipelined multi-tile) ----------------
// Grid-stride blocks; W1 register-resident; double-buffered hA; W2 rolling
// quarter prefetch; 2 barriers/tile (x1s is wave-stripe-partitioned: epi2->pool
// and pool->next-epi1 are same-wave LDS deps, program-order safe).
__global__ __launch_bounds__(256, 2)
void node_kernel(const float* __restrict__ h, const int* __restrict__ gids,
                 const float* __restrict__ b1, const float* __restrict__ b2,
                 const unsigned short* __restrict__ W1t, const unsigned short* __restrict__ W2t,
                 float* __restrict__ pooled, int nnodes, int ntiles) {
  __shared__ unsigned short hA[2][BM * D_IN];   // 2 x 16 KB, swizzled [row][k]
  __shared__ unsigned short x1s[BM * D_H];      // 32 KB, swizzled [row][f]; x1 then x2
  __shared__ int sgid[2][BM];
  const int tid  = threadIdx.x;
  const int lane = tid & 63;
  const int wave = tid >> 6;
  const int lr   = lane & 15;
  const int q    = lane >> 4;

  if (blockIdx.x >= ntiles) return;

  // ---- persistent registers: W1 A-frags (64 VGPR) + biases (32 VGPR)
  s16x8 a1[4][4];
  #pragma unroll
  for (int ks = 0; ks < 4; ++ks)
    #pragma unroll
    for (int mt = 0; mt < 4; ++mt)
      a1[ks][mt] = *(const s16x8*)&W1t[(wave * 64 + mt * 16 + lr) * D_IN + ks * 32 + q * 8];
  float4 b1v[4], b2v[4];
  #pragma unroll
  for (int mt = 0; mt < 4; ++mt) {
    b1v[mt] = *(const float4*)&b1[wave * 64 + mt * 16 + q * 4];
    b2v[mt] = *(const float4*)&b2[wave * 64 + mt * 16 + q * 4];
  }

  int tile = blockIdx.x;

  // ---- prologue: stage first tile into buffer 0
  {
    const int row0 = tile * BM;
    #pragma unroll
    for (int i = 0; i < 4; ++i) {
      int gi = tid + i * 256, r = gi >> 4, gc = gi & 15, gr = row0 + r;
      f32x4 v0 = (f32x4){0.f, 0.f, 0.f, 0.f}, v1 = v0;
      if (gr < nnodes) {
        const f32x4* p = (const f32x4*)(h + (size_t)gr * D_IN + gc * 8);
        v0 = __builtin_nontemporal_load(p);
        v1 = __builtin_nontemporal_load(p + 1);
      }
      u32x4 u;
      u[0] = f2bf(v0[0]) | ((uint32_t)f2bf(v0[1]) << 16);
      u[1] = f2bf(v0[2]) | ((uint32_t)f2bf(v0[3]) << 16);
      u[2] = f2bf(v1[0]) | ((uint32_t)f2bf(v1[1]) << 16);
      u[3] = f2bf(v1[2]) | ((uint32_t)f2bf(v1[3]) << 16);
      *(u32x4*)&hA[0][r * D_IN + ((gc ^ (r & 7)) << 3)] = u;
    }
    if (tid < BM) {
      int gr = row0 + tid;
      sgid[0][tid] = (gr < nnodes) ? gids[gr] : -1;
    }
  }
  __syncthreads();

  auto body = [&](int cur) {
    const int nxt = cur ^ 1;
    const int ntile = tile + NODE_GRID;
    const bool has_next = ntile < ntiles;
    const int nrow0 = ntile * BM;

    // -- prefetch next tile's h rows (+ graph ids) into registers
    f32x4 hv[8];
    #pragma unroll
    for (int i = 0; i < 4; ++i) {
      int gi = tid + i * 256, r = gi >> 4, gc = gi & 15;
      int gr = nrow0 + r;
      hv[2 * i] = (f32x4){0.f, 0.f, 0.f, 0.f};
      hv[2 * i + 1] = hv[2 * i];
      if (has_next && gr < nnodes) {
        const f32x4* p = (const f32x4*)(h + (size_t)gr * D_IN + gc * 8);
        hv[2 * i]     = __builtin_nontemporal_load(p);
        hv[2 * i + 1] = __builtin_nontemporal_load(p + 1);
      }
    }
    int gv = -1;
    if (has_next && tid < BM) {
      int gr = nrow0 + tid;
      gv = (gr < nnodes) ? gids[gr] : -1;
    }

    f32x4 acc[4][4];
    #pragma unroll
    for (int mt = 0; mt < 4; ++mt)
      #pragma unroll
      for (int nt = 0; nt < 4; ++nt)
        acc[mt][nt] = (f32x4){0.f, 0.f, 0.f, 0.f};

    // -- layer 1 (W1 resident, B from hA[cur])
    #pragma unroll
    for (int ks = 0; ks < 4; ++ks) {
      const int kq = ks * 32 + q * 8;
      s16x8 b[4];
      #pragma unroll
      for (int nt = 0; nt < 4; ++nt)
        b[nt] = *(const s16x8*)&hA[cur][(nt * 16 + lr) * D_IN + (((kq >> 3) ^ (lr & 7)) << 3)];
      #pragma unroll
      for (int mt = 0; mt < 4; ++mt)
        #pragma unroll
        for (int nt = 0; nt < 4; ++nt)
          acc[mt][nt] = __builtin_amdgcn_mfma_f32_16x16x32_bf16(a1[ks][mt], b[nt], acc[mt][nt], 0, 0, 0);
    }

    // -- epilogue 1: relu(+b1) -> x1s (own wave's feature stripe)
    #pragma unroll
    for (int mt = 0; mt < 4; ++mt) {
      int f = wave * 64 + mt * 16 + q * 4;
      #pragma unroll
      for (int nt = 0; nt < 4; ++nt) {
        int nd = nt * 16 + lr;
        uint32_t p0 = f2bf(fmaxf(acc[mt][nt][0] + b1v[mt].x, 0.f)) |
                      ((uint32_t)f2bf(fmaxf(acc[mt][nt][1] + b1v[mt].y, 0.f)) << 16);
        uint32_t p1 = f2bf(fmaxf(acc[mt][nt][2] + b1v[mt].z, 0.f)) |
                      ((uint32_t)f2bf(fmaxf(acc[mt][nt][3] + b1v[mt].w, 0.f)) << 16);
        u32x2 w = {p0, p1};
        *(u32x2*)&x1s[nd * D_H + (((f >> 3) ^ (nd & 7)) << 3) + (f & 7)] = w;
      }
    }

    // -- stage next tile into hA[nxt] (safe: its last readers were 2 barriers ago)
    if (has_next) {
      #pragma unroll
      for (int i = 0; i < 4; ++i) {
        int gi = tid + i * 256, r = gi >> 4, gc = gi & 15;
        u32x4 u;
        u[0] = f2bf(hv[2 * i][0]) | ((uint32_t)f2bf(hv[2 * i][1]) << 16);
        u[1] = f2bf(hv[2 * i][2]) | ((uint32_t)f2bf(hv[2 * i][3]) << 16);
        u[2] = f2bf(hv[2 * i + 1][0]) | ((uint32_t)f2bf(hv[2 * i + 1][1]) << 16);
        u[3] = f2bf(hv[2 * i + 1][2]) | ((uint32_t)f2bf(hv[2 * i + 1][3]) << 16);
        *(u32x4*)&hA[nxt][r * D_IN + ((gc ^ (r & 7)) << 3)] = u;
      }
    }

    // -- preload W2 quarters 0,1 (rolling buffers)
    s16x8 w2[2][2][4];
    #pragma unroll
    for (int qq = 0; qq < 2; ++qq)
      #pragma unroll
      for (int ki = 0; ki < 2; ++ki)
        #pragma unroll
        for (int mt = 0; mt < 4; ++mt)
          w2[qq][ki][mt] = *(const s16x8*)&W2t[(wave * 64 + mt * 16 + lr) * D_H +
                                               ((qq * 2 + ki) * 32 + q * 8)];

    __syncthreads();   // B1: x1 writes -> cross-wave x1 reads

    #pragma unroll
    for (int mt = 0; mt < 4; ++mt)
      #pragma unroll
      for (int nt = 0; nt < 4; ++nt)
        acc[mt][nt] = (f32x4){0.f, 0.f, 0.f, 0.f};

    // -- layer 2: 4 quarters with depth-2 rolling A prefetch
    #pragma unroll
    for (int qq = 0; qq < 4; ++qq) {
      const int buf = qq & 1;
      #pragma unroll
      for (int ki = 0; ki < 2; ++ki) {
        const int kq = (qq * 2 + ki) * 32 + q * 8;
        s16x8 b[4];
        #pragma unroll
        for (int nt = 0; nt < 4; ++nt)
          b[nt] = *(const s16x8*)&x1s[(nt * 16 + lr) * D_H + (((kq >> 3) ^ (lr & 7)) << 3)];
        #pragma unroll
        for (int mt = 0; mt < 4; ++mt)
          #pragma unroll
          for (int nt = 0; nt < 4; ++nt)
            acc[mt][nt] = __builtin_amdgcn_mfma_f32_16x16x32_bf16(w2[buf][ki][mt], b[nt], acc[mt][nt], 0, 0, 0);
      }
      if (qq < 2) {
        #pragma unroll
        for (int ki = 0; ki < 2; ++ki)
          #pragma unroll
          for (int mt = 0; mt < 4; ++mt)
            w2[buf][ki][mt] = *(const s16x8*)&W2t[(wave * 64 + mt * 16 + lr) * D_H +
                                                  (((qq + 2) * 2 + ki) * 32 + q * 8)];
      }
    }

    __syncthreads();   // B2: cross-wave x1 reads -> x2 writes

    if (has_next && tid < BM) sgid[nxt][tid] = gv;

    // -- epilogue 2: relu(+b2) -> x2 bf16 into x1s (own stripe)
    #pragma unroll
    for (int mt = 0; mt < 4; ++mt) {
      int f = wave * 64 + mt * 16 + q * 4;
      #pragma unroll
      for (int nt = 0; nt < 4; ++nt) {
        int nd = nt * 16 + lr;
        uint32_t p0 = f2bf(fmaxf(acc[mt][nt][0] + b2v[mt].x, 0.f)) |
                      ((uint32_t)f2bf(fmaxf(acc[mt][nt][1] + b2v[mt].y, 0.f)) << 16);
        uint32_t p1 = f2bf(fmaxf(acc[mt][nt][2] + b2v[mt].z, 0.f)) |
                      ((uint32_t)f2bf(fmaxf(acc[mt][nt][3] + b2v[mt].w, 0.f)) << 16);
        u32x2 w = {p0, p1};
        *(u32x2*)&x1s[nd * D_H + (((f >> 3) ^ (nd & 7)) << 3) + (f & 7)] = w;
      }
    }

    // -- pooling: thread tid reads feature tid = own wave's stripe (no barrier
    //    needed: same-wave LDS program order). Sorted gids -> run detection.
    float racc = 0.f;
    for (int r = 0; r < BM; ++r) {
      int g = sgid[cur][r];
      if (g >= 0) {
        racc += bf2f(x1s[r * D_H + (((tid >> 3) ^ (r & 7)) << 3) + (tid & 7)]);
        if (r == BM - 1 || sgid[cur][r + 1] != g) {
          atomicAdd(&pooled[g * D_H + tid], racc);
          racc = 0.f;
        }
      }
    }
  };

  while (true) {
    body(0);
    tile += NODE_GRID;
    if (tile >= ntiles) break;
    body(1);
    tile += NODE_GRID;
    if (tile >= ntiles) break;
  }
}

// ---------------- graph MLP: swizzled 32 KB LDS, bf16 y, conflict-free ----------------
__global__ __launch_bounds__(256, 4)
void graph_kernel(const float* __restrict__ pooled, const float* __restrict__ bg1,
                  const unsigned short* __restrict__ Wg1t, const float* __restrict__ Wg2,
                  const float* __restrict__ bg2, float* __restrict__ out, int ngraphs) {
  __shared__ unsigned short pA[BM * D_H];   // 32 KB swizzled; pooled-bf16 then y-bf16
  const int tid  = threadIdx.x;
  const int lane = tid & 63;
  const int wave = tid >> 6;
  const int lr   = lane & 15;
  const int q    = lane >> 4;
  const int g0   = blockIdx.x * BM;

  // stage pooled (fp32 -> bf16), swizzled 16B granules: 64 rows x 32 granules
  #pragma unroll
  for (int i = 0; i < 8; ++i) {
    int gi = tid + i * 256, r = gi >> 5, gc = gi & 31;
    int gr = g0 + r;
    f32x4 v0 = (f32x4){0.f, 0.f, 0.f, 0.f}, v1 = v0;
    if (gr < ngraphs) {
      const f32x4* p = (const f32x4*)(pooled + (size_t)gr * D_H + gc * 8);
      v0 = p[0]; v1 = p[1];
    }
    u32x4 u;
    u[0] = f2bf(v0[0]) | ((uint32_t)f2bf(v0[1]) << 16);
    u[1] = f2bf(v0[2]) | ((uint32_t)f2bf(v0[3]) << 16);
    u[2] = f2bf(v1[0]) | ((uint32_t)f2bf(v1[1]) << 16);
    u[3] = f2bf(v1[2]) | ((uint32_t)f2bf(v1[3]) << 16);
    *(u32x4*)&pA[r * D_H + (((gc & 7) ^ (r & 7)) << 3) + ((gc & 24) << 3)] = u;
  }
  __syncthreads();

  f32x4 acc[4][4];
  #pragma unroll
  for (int mt = 0; mt < 4; ++mt)
    #pragma unroll
    for (int nt = 0; nt < 4; ++nt)
      acc[mt][nt] = (f32x4){0.f, 0.f, 0.f, 0.f};

  #pragma unroll
  for (int ks = 0; ks < 8; ++ks) {
    const int kq = ks * 32 + q * 8;
    s16x8 a[4], b[4];
    #pragma unroll
    for (int mt = 0; mt < 4; ++mt)
      a[mt] = *(const s16x8*)&Wg1t[(wave * 64 + mt * 16 + lr) * D_H + kq];
    #pragma unroll
    for (int nt = 0; nt < 4; ++nt) {
      int row = nt * 16 + lr, gw = kq >> 3;
      b[nt] = *(const s16x8*)&pA[row * D_H + (((gw & 7) ^ (row & 7)) << 3) + ((gw & 24) << 3)];
    }
    #pragma unroll
    for (int mt = 0; mt < 4; ++mt)
      #pragma unroll
      for (int nt = 0; nt < 4; ++nt)
        acc[mt][nt] = __builtin_amdgcn_mfma_f32_16x16x32_bf16(a[mt], b[nt], acc[mt][nt], 0, 0, 0);
  }
  __syncthreads();   // all pA reads done; overwrite with y

  #pragma unroll
  for (int mt = 0; mt < 4; ++mt) {
    int f = wave * 64 + mt * 16 + q * 4;
    float4 bias = *(const float4*)&bg1[f];
    #pragma unroll
    for (int nt = 0; nt < 4; ++nt) {
      int nd = nt * 16 + lr;
      uint32_t p0 = f2bf(fmaxf(acc[mt][nt][0] + bias.x, 0.f)) |
                    ((uint32_t)f2bf(fmaxf(acc[mt][nt][1] + bias.y, 0.f)) << 16);
      uint32_t p1 = f2bf(fmaxf(acc[mt][nt][2] + bias.z, 0.f)) |
                    ((uint32_t)f2bf(fmaxf(acc[mt][nt][3] + bias.w, 0.f)) << 16);
      u32x2 w = {p0, p1};
      int gw = f >> 3;
      *(u32x2*)&pA[nd * D_H + (((gw & 7) ^ (nd & 7)) << 3) + ((gw & 24) << 3) + (f & 7)] = w;
    }
  }
  __syncthreads();

  // out[g] = y[g,:] . Wg2 + bg2 ; 4 threads/graph, u32 (2 bf16) per read
  int gloc = tid >> 2;
  int part = tid & 3;
  float p = 0.f;
  #pragma unroll 8
  for (int i = 0; i < 32; ++i) {
    int f2 = part + 4 * i;             // feature-pair index
    int hw = 2 * f2;                   // halfword index within row
    int gw = hw >> 3;
    uint32_t wv = *(const uint32_t*)&pA[gloc * D_H + (((gw & 7) ^ (gloc & 7)) << 3) +
                                        ((gw & 24) << 3) + (hw & 7)];
    float2 wg = ((const float2*)Wg2)[f2];
    p += bf2f((unsigned short)(wv & 0xffffu)) * wg.x +
         bf2f((unsigned short)(wv >> 16)) * wg.y;
  }
  p += __shfl_xor(p, 1);
  p += __shfl_xor(p, 2);
  if (part == 0 && (g0 + gloc) < ngraphs)
    out[g0 + gloc] = p + bg2[0];
}

extern "C" void kernel_launch(void* const* d_in, const int* in_sizes, int n_in,
                              void* d_out, int out_size, void* d_ws, size_t ws_size,
                              hipStream_t stream) {
  const float* h   = (const float*)d_in[0];
  const int*   gid = (const int*)d_in[1];
  const float* W1  = (const float*)d_in[3];
  const float* b1  = (const float*)d_in[4];
  const float* W2  = (const float*)d_in[5];
  const float* b2  = (const float*)d_in[6];
  const float* Wg1 = (const float*)d_in[7];
  const float* bg1 = (const float*)d_in[8];
  const float* Wg2 = (const float*)d_in[9];
  const float* bg2 = (const float*)d_in[10];
  float* out = (float*)d_out;

  const int N = in_sizes[1];
  const int G = out_size;
  const int ntiles = (N + BM - 1) / BM;

  char* ws = (char*)d_ws;
  float* pooled = (float*)ws;                                   // G*256*4 = 20.48 MB
  size_t off = (size_t)G * D_H * sizeof(float);
  unsigned short* W1t  = (unsigned short*)(ws + off); off += (size_t)D_H * D_IN * 2;
  unsigned short* W2t  = (unsigned short*)(ws + off); off += (size_t)D_H * D_H * 2;
  unsigned short* Wg1t = (unsigned short*)(ws + off);

  prep_kernel<<<512, 256, 0, stream>>>(W1, W2, Wg1, pooled, W1t, W2t, Wg1t, G * D_H);
  node_kernel<<<NODE_GRID, 256, 0, stream>>>(h, gid, b1, b2, W1t, W2t, pooled, N, ntiles);
  graph_kernel<<<(G + BM - 1) / BM, 256, 0, stream>>>(pooled, bg1, Wg1t, Wg2, bg2, out, G);
}

// Round 4
// 791.780 us; speedup vs baseline: 1.0217x; 1.0217x over previous
//
#include <hip/hip_runtime.h>
#include <stdint.h>

#define D_IN 128
#define D_H  256
#define BM   64
#define NB   512   // node grid: 2 blocks/CU

typedef float f32x4 __attribute__((ext_vector_type(4)));
typedef short s16x8 __attribute__((ext_vector_type(8)));
typedef unsigned int u32x2 __attribute__((ext_vector_type(2)));
typedef unsigned int u32x4 __attribute__((ext_vector_type(4)));

__device__ __forceinline__ unsigned short f2bf(float x) {
  union { float f; uint32_t u; } v; v.f = x;
  uint32_t r = v.u + 0x7fffu + ((v.u >> 16) & 1u);   // RNE
  return (unsigned short)(r >> 16);
}
__device__ __forceinline__ float bf2f(unsigned short u) {
  union { uint32_t u; float f; } v; v.u = (uint32_t)u << 16;
  return v.f;
}
// pack 2 fp32 -> 2 bf16 (RNE). HW v_cvt_pk_bf16_f32 when available.
__device__ __forceinline__ uint32_t pkbf(float lo, float hi) {
#if __has_builtin(__builtin_amdgcn_cvt_pk_bf16_f32)
  auto r = __builtin_amdgcn_cvt_pk_bf16_f32(lo, hi);
  uint32_t u; __builtin_memcpy(&u, &r, 4); return u;
#else
  return (uint32_t)f2bf(lo) | ((uint32_t)f2bf(hi) << 16);
#endif
}

// ---------------- prep: zero pooled accumulator, cast/transpose weights ----------------
__global__ void prep_kernel(const float* __restrict__ W1, const float* __restrict__ W2,
                            const float* __restrict__ Wg1,
                            float* __restrict__ pooled, unsigned short* __restrict__ W1t,
                            unsigned short* __restrict__ W2t, unsigned short* __restrict__ Wg1t,
                            int pooled_n) {
  int stride = gridDim.x * blockDim.x;
  int tid = blockIdx.x * blockDim.x + threadIdx.x;
  float4 z4 = make_float4(0.f, 0.f, 0.f, 0.f);
  for (int i = tid; i < (pooled_n >> 2); i += stride) ((float4*)pooled)[i] = z4;
  for (int i = tid; i < D_H * D_IN; i += stride) {
    int n = i >> 7, k = i & (D_IN - 1);
    W1t[i] = f2bf(W1[k * D_H + n]);
  }
  for (int i = tid; i < D_H * D_H; i += stride) {
    int n = i >> 8, k = i & (D_H - 1);
    W2t[i]  = f2bf(W2[k * D_H + n]);
    Wg1t[i] = f2bf(Wg1[k * D_H + n]);
  }
}

// ---------------- node MLP + fused segment-sum ----------------
// Pipelined grid-stride tiles with ONE time-multiplexed 64-VGPR weight buffer:
//   wb = W1(ks0-3) -> L1 -> wb = W2 ks01/23 -> B1 -> L2 (roll ks45/67 into
//   consumed slots) -> B2 -> wb = next W1 (issued before epi2, ~800cyc slack).
// h prefetch: fp32 loads at loop top (hv, 32 VGPR) -> cvt to hu (16 VGPR)
// mid-L1 -> written to single hA buffer after B1 (L1 readers done).
// 2 barriers/tile; x1s stripe-partitioned so epi2->pool->next-epi1 are
// same-wave LDS deps (program order). LDS 48.5 KB; VGPR ~235 -> 8 waves/CU.

#define L1STEP(ks)                                                                       \
  do {                                                                                   \
    s16x8 bb[4];                                                                         \
    _Pragma("unroll")                                                                    \
    for (int nt = 0; nt < 4; ++nt) {                                                     \
      int nd = nt * 16 + lr;                                                             \
      bb[nt] = *(const s16x8*)&hA[nd * D_IN + ((((ks) * 4 + q) ^ sw) << 3)];             \
    }                                                                                    \
    _Pragma("unroll")                                                                    \
    for (int mt = 0; mt < 4; ++mt)                                                       \
      _Pragma("unroll")                                                                  \
      for (int nt = 0; nt < 4; ++nt)                                                     \
        acc[mt][nt] = __builtin_amdgcn_mfma_f32_16x16x32_bf16(wb[ks][mt], bb[nt],        \
                                                              acc[mt][nt], 0, 0, 0);    \
  } while (0)

#define L2STEP(ks, slot)                                                                 \
  do {                                                                                   \
    s16x8 bb[4];                                                                         \
    _Pragma("unroll")                                                                    \
    for (int nt = 0; nt < 4; ++nt) {                                                     \
      int nd = nt * 16 + lr;                                                             \
      bb[nt] = *(const s16x8*)&x1s[nd * D_H + ((((ks) * 4 + q) ^ sw) << 3)];             \
    }                                                                                    \
    _Pragma("unroll")                                                                    \
    for (int mt = 0; mt < 4; ++mt)                                                       \
      _Pragma("unroll")                                                                  \
      for (int nt = 0; nt < 4; ++nt)                                                     \
        acc[mt][nt] = __builtin_amdgcn_mfma_f32_16x16x32_bf16(wb[slot][mt], bb[nt],      \
                                                              acc[mt][nt], 0, 0, 0);    \
  } while (0)

__global__ __launch_bounds__(256, 2)
void node_kernel(const float* __restrict__ h, const int* __restrict__ gids,
                 const float* __restrict__ b1, const float* __restrict__ b2,
                 const unsigned short* __restrict__ W1t, const unsigned short* __restrict__ W2t,
                 float* __restrict__ pooled, int nnodes, int ntiles) {
  __shared__ unsigned short hA[BM * D_IN];    // 16 KB swizzled [row][k]
  __shared__ unsigned short x1s[BM * D_H];    // 32 KB swizzled [row][f]; x1 then x2
  __shared__ int sgid[2][BM];
  const int tid  = threadIdx.x;
  const int lane = tid & 63;
  const int wave = tid >> 6;
  const int lr   = lane & 15;
  const int q    = lane >> 4;
  const int sw   = lr & 7;

  if (blockIdx.x >= ntiles) return;

  const unsigned short* w1p = W1t + (wave * 64 + lr) * D_IN + q * 8;
  const unsigned short* w2p = W2t + (wave * 64 + lr) * D_H + q * 8;

  int tile = blockIdx.x;
  int par  = 0;

  // weight buffer: load W1 for first tile
  s16x8 wb[4][4];
  #pragma unroll
  for (int ks = 0; ks < 4; ++ks)
    #pragma unroll
    for (int mt = 0; mt < 4; ++mt)
      wb[ks][mt] = *(const s16x8*)(w1p + mt * 16 * D_IN + ks * 32);

  // prologue: stage tile 0 h + gids
  {
    const int row0 = tile * BM;
    #pragma unroll
    for (int i = 0; i < 4; ++i) {
      int gi = tid + i * 256, r = gi >> 4, gc = gi & 15, gr = row0 + r;
      f32x4 v0 = (f32x4){0.f, 0.f, 0.f, 0.f}, v1 = v0;
      if (gr < nnodes) {
        const f32x4* p = (const f32x4*)(h + (size_t)gr * D_IN + gc * 8);
        v0 = __builtin_nontemporal_load(p);
        v1 = __builtin_nontemporal_load(p + 1);
      }
      u32x4 u;
      u[0] = pkbf(v0[0], v0[1]); u[1] = pkbf(v0[2], v0[3]);
      u[2] = pkbf(v1[0], v1[1]); u[3] = pkbf(v1[2], v1[3]);
      *(u32x4*)&hA[r * D_IN + ((gc ^ (r & 7)) << 3)] = u;
    }
    if (tid < BM) {
      int gr = row0 + tid;
      sgid[0][tid] = (gr < nnodes) ? gids[gr] : -1;
    }
  }
  __syncthreads();

  while (true) {
    const int  ntile    = tile + NB;
    const bool has_next = ntile < ntiles;

    // ---- P0: prefetch next tile h (fp32) + gid; b1v for epi1
    f32x4 hv[8];
    #pragma unroll
    for (int i = 0; i < 8; ++i) hv[i] = (f32x4){0.f, 0.f, 0.f, 0.f};
    if (has_next) {
      const int nrow0 = ntile * BM;
      #pragma unroll
      for (int i = 0; i < 4; ++i) {
        int gi = tid + i * 256, r = gi >> 4, gc = gi & 15, gr = nrow0 + r;
        if (gr < nnodes) {
          const f32x4* p = (const f32x4*)(h + (size_t)gr * D_IN + gc * 8);
          hv[2 * i]     = __builtin_nontemporal_load(p);
          hv[2 * i + 1] = __builtin_nontemporal_load(p + 1);
        }
      }
    }
    int gv = -1;
    if (has_next && tid < BM) {
      int gr = ntile * BM + tid;
      gv = (gr < nnodes) ? gids[gr] : -1;
    }
    float4 b1v[4];
    #pragma unroll
    for (int mt = 0; mt < 4; ++mt)
      b1v[mt] = *(const float4*)&b1[wave * 64 + mt * 16 + q * 4];

    // ---- L1 (wb = W1), hv->hu conversion interleaved after ks1
    f32x4 acc[4][4];
    #pragma unroll
    for (int mt = 0; mt < 4; ++mt)
      #pragma unroll
      for (int nt = 0; nt < 4; ++nt)
        acc[mt][nt] = (f32x4){0.f, 0.f, 0.f, 0.f};

    L1STEP(0);
    L1STEP(1);
    u32x4 hu[4];
    #pragma unroll
    for (int i = 0; i < 4; ++i) {
      hu[i][0] = pkbf(hv[2 * i][0], hv[2 * i][1]);
      hu[i][1] = pkbf(hv[2 * i][2], hv[2 * i][3]);
      hu[i][2] = pkbf(hv[2 * i + 1][0], hv[2 * i + 1][1]);
      hu[i][3] = pkbf(hv[2 * i + 1][2], hv[2 * i + 1][3]);
    }
    L1STEP(2);
    L1STEP(3);

    // ---- epi1: relu(+b1) -> x1s (own wave stripe)
    #pragma unroll
    for (int mt = 0; mt < 4; ++mt) {
      int f = wave * 64 + mt * 16 + q * 4;
      #pragma unroll
      for (int nt = 0; nt < 4; ++nt) {
        int nd = nt * 16 + lr;
        u32x2 w;
        w[0] = pkbf(fmaxf(acc[mt][nt][0] + b1v[mt].x, 0.f),
                    fmaxf(acc[mt][nt][1] + b1v[mt].y, 0.f));
        w[1] = pkbf(fmaxf(acc[mt][nt][2] + b1v[mt].z, 0.f),
                    fmaxf(acc[mt][nt][3] + b1v[mt].w, 0.f));
        *(u32x2*)&x1s[nd * D_H + (((f >> 3) ^ (nd & 7)) << 3) + (f & 7)] = w;
      }
    }

    // ---- refill wb with W2 ks0..3 (consumed after B1)
    #pragma unroll
    for (int ks = 0; ks < 4; ++ks)
      #pragma unroll
      for (int mt = 0; mt < 4; ++mt)
        wb[ks][mt] = *(const s16x8*)(w2p + mt * 16 * D_H + ks * 32);

    __syncthreads();   // B1: x1 publish + hA readers done

    // ---- P3: next h tile -> hA; next gids -> sgid[par^1]
    if (has_next) {
      #pragma unroll
      for (int i = 0; i < 4; ++i) {
        int gi = tid + i * 256, r = gi >> 4, gc = gi & 15;
        *(u32x4*)&hA[r * D_IN + ((gc ^ (r & 7)) << 3)] = hu[i];
      }
      if (tid < BM) sgid[par ^ 1][tid] = gv;
    }
    float4 b2v[4];
    #pragma unroll
    for (int mt = 0; mt < 4; ++mt)
      b2v[mt] = *(const float4*)&b2[wave * 64 + mt * 16 + q * 4];

    // ---- L2: 8 k-steps, rolling refill of consumed slots
    #pragma unroll
    for (int mt = 0; mt < 4; ++mt)
      #pragma unroll
      for (int nt = 0; nt < 4; ++nt)
        acc[mt][nt] = (f32x4){0.f, 0.f, 0.f, 0.f};

    L2STEP(0, 0);
    L2STEP(1, 1);
    #pragma unroll
    for (int mt = 0; mt < 4; ++mt) {
      wb[0][mt] = *(const s16x8*)(w2p + mt * 16 * D_H + 4 * 32);
      wb[1][mt] = *(const s16x8*)(w2p + mt * 16 * D_H + 5 * 32);
    }
    L2STEP(2, 2);
    L2STEP(3, 3);
    #pragma unroll
    for (int mt = 0; mt < 4; ++mt) {
      wb[2][mt] = *(const s16x8*)(w2p + mt * 16 * D_H + 6 * 32);
      wb[3][mt] = *(const s16x8*)(w2p + mt * 16 * D_H + 7 * 32);
    }
    L2STEP(4, 0);
    L2STEP(5, 1);
    L2STEP(6, 2);
    L2STEP(7, 3);

    __syncthreads();   // B2: x1 readers done -> x2 writes allowed

    // ---- issue next tile's W1 now (consumed after epi2+pool: big slack)
    if (has_next) {
      #pragma unroll
      for (int ks = 0; ks < 4; ++ks)
        #pragma unroll
        for (int mt = 0; mt < 4; ++mt)
          wb[ks][mt] = *(const s16x8*)(w1p + mt * 16 * D_IN + ks * 32);
    }

    // ---- epi2: relu(+b2) -> x2 bf16 into x1s (own stripe)
    #pragma unroll
    for (int mt = 0; mt < 4; ++mt) {
      int f = wave * 64 + mt * 16 + q * 4;
      #pragma unroll
      for (int nt = 0; nt < 4; ++nt) {
        int nd = nt * 16 + lr;
        u32x2 w;
        w[0] = pkbf(fmaxf(acc[mt][nt][0] + b2v[mt].x, 0.f),
                    fmaxf(acc[mt][nt][1] + b2v[mt].y, 0.f));
        w[1] = pkbf(fmaxf(acc[mt][nt][2] + b2v[mt].z, 0.f),
                    fmaxf(acc[mt][nt][3] + b2v[mt].w, 0.f));
        *(u32x2*)&x1s[nd * D_H + (((f >> 3) ^ (nd & 7)) << 3) + (f & 7)] = w;
      }
    }

    // ---- pool: thread tid = feature tid (own wave stripe; same-wave LDS order)
    {
      const int hi = tid >> 3, lo = tid & 7;
      float racc = 0.f;
      for (int r = 0; r < BM; ++r) {
        int g = sgid[par][r];
        if (g >= 0) {
          racc += bf2f(x1s[r * D_H + ((hi ^ (r & 7)) << 3) + lo]);
          if (r == BM - 1 || sgid[par][r + 1] != g) {
            atomicAdd(&pooled[g * D_H + tid], racc);
            racc = 0.f;
          }
        }
      }
    }

    if (!has_next) break;
    tile = ntile;
    par ^= 1;
  }
}

// ---------------- graph MLP: swizzled 32 KB LDS, bf16 y, conflict-free ----------------
__global__ __launch_bounds__(256, 4)
void graph_kernel(const float* __restrict__ pooled, const float* __restrict__ bg1,
                  const unsigned short* __restrict__ Wg1t, const float* __restrict__ Wg2,
                  const float* __restrict__ bg2, float* __restrict__ out, int ngraphs) {
  __shared__ unsigned short pA[BM * D_H];   // 32 KB swizzled; pooled-bf16 then y-bf16
  const int tid  = threadIdx.x;
  const int lane = tid & 63;
  const int wave = tid >> 6;
  const int lr   = lane & 15;
  const int q    = lane >> 4;
  const int g0   = blockIdx.x * BM;

  #pragma unroll
  for (int i = 0; i < 8; ++i) {
    int gi = tid + i * 256, r = gi >> 5, gc = gi & 31;
    int gr = g0 + r;
    f32x4 v0 = (f32x4){0.f, 0.f, 0.f, 0.f}, v1 = v0;
    if (gr < ngraphs) {
      const f32x4* p = (const f32x4*)(pooled + (size_t)gr * D_H + gc * 8);
      v0 = p[0]; v1 = p[1];
    }
    u32x4 u;
    u[0] = pkbf(v0[0], v0[1]); u[1] = pkbf(v0[2], v0[3]);
    u[2] = pkbf(v1[0], v1[1]); u[3] = pkbf(v1[2], v1[3]);
    *(u32x4*)&pA[r * D_H + (((gc & 7) ^ (r & 7)) << 3) + ((gc & 24) << 3)] = u;
  }
  __syncthreads();

  f32x4 acc[4][4];
  #pragma unroll
  for (int mt = 0; mt < 4; ++mt)
    #pragma unroll
    for (int nt = 0; nt < 4; ++nt)
      acc[mt][nt] = (f32x4){0.f, 0.f, 0.f, 0.f};

  #pragma unroll
  for (int ks = 0; ks < 8; ++ks) {
    const int kq = ks * 32 + q * 8;
    s16x8 a[4], b[4];
    #pragma unroll
    for (int mt = 0; mt < 4; ++mt)
      a[mt] = *(const s16x8*)&Wg1t[(wave * 64 + mt * 16 + lr) * D_H + kq];
    #pragma unroll
    for (int nt = 0; nt < 4; ++nt) {
      int row = nt * 16 + lr, gw = kq >> 3;
      b[nt] = *(const s16x8*)&pA[row * D_H + (((gw & 7) ^ (row & 7)) << 3) + ((gw & 24) << 3)];
    }
    #pragma unroll
    for (int mt = 0; mt < 4; ++mt)
      #pragma unroll
      for (int nt = 0; nt < 4; ++nt)
        acc[mt][nt] = __builtin_amdgcn_mfma_f32_16x16x32_bf16(a[mt], b[nt], acc[mt][nt], 0, 0, 0);
  }
  __syncthreads();   // all pA reads done; overwrite with y

  #pragma unroll
  for (int mt = 0; mt < 4; ++mt) {
    int f = wave * 64 + mt * 16 + q * 4;
    float4 bias = *(const float4*)&bg1[f];
    #pragma unroll
    for (int nt = 0; nt < 4; ++nt) {
      int nd = nt * 16 + lr;
      u32x2 w;
      w[0] = pkbf(fmaxf(acc[mt][nt][0] + bias.x, 0.f),
                  fmaxf(acc[mt][nt][1] + bias.y, 0.f));
      w[1] = pkbf(fmaxf(acc[mt][nt][2] + bias.z, 0.f),
                  fmaxf(acc[mt][nt][3] + bias.w, 0.f));
      int gw = f >> 3;
      *(u32x2*)&pA[nd * D_H + (((gw & 7) ^ (nd & 7)) << 3) + ((gw & 24) << 3) + (f & 7)] = w;
    }
  }
  __syncthreads();

  int gloc = tid >> 2;
  int part = tid & 3;
  float p = 0.f;
  #pragma unroll 8
  for (int i = 0; i < 32; ++i) {
    int f2 = part + 4 * i;
    int hw = 2 * f2;
    int gw = hw >> 3;
    uint32_t wv = *(const uint32_t*)&pA[gloc * D_H + (((gw & 7) ^ (gloc & 7)) << 3) +
                                        ((gw & 24) << 3) + (hw & 7)];
    float2 wg = ((const float2*)Wg2)[f2];
    p += bf2f((unsigned short)(wv & 0xffffu)) * wg.x +
         bf2f((unsigned short)(wv >> 16)) * wg.y;
  }
  p += __shfl_xor(p, 1);
  p += __shfl_xor(p, 2);
  if (part == 0 && (g0 + gloc) < ngraphs)
    out[g0 + gloc] = p + bg2[0];
}

extern "C" void kernel_launch(void* const* d_in, const int* in_sizes, int n_in,
                              void* d_out, int out_size, void* d_ws, size_t ws_size,
                              hipStream_t stream) {
  const float* h   = (const float*)d_in[0];
  const int*   gid = (const int*)d_in[1];
  const float* W1  = (const float*)d_in[3];
  const float* b1  = (const float*)d_in[4];
  const float* W2  = (const float*)d_in[5];
  const float* b2  = (const float*)d_in[6];
  const float* Wg1 = (const float*)d_in[7];
  const float* bg1 = (const float*)d_in[8];
  const float* Wg2 = (const float*)d_in[9];
  const float* bg2 = (const float*)d_in[10];
  float* out = (float*)d_out;

  const int N = in_sizes[1];
  const int G = out_size;
  const int ntiles = (N + BM - 1) / BM;

  char* ws = (char*)d_ws;
  float* pooled = (float*)ws;                                   // G*256*4 = 20.48 MB
  size_t off = (size_t)G * D_H * sizeof(float);
  unsigned short* W1t  = (unsigned short*)(ws + off); off += (size_t)D_H * D_IN * 2;
  unsigned short* W2t  = (unsigned short*)(ws + off); off += (size_t)D_H * D_H * 2;
  unsigned short* Wg1t = (unsigned short*)(ws + off);

  prep_kernel<<<512, 256, 0, stream>>>(W1, W2, Wg1, pooled, W1t, W2t, Wg1t, G * D_H);
  node_kernel<<<NB, 256, 0, stream>>>(h, gid, b1, b2, W1t, W2t, pooled, N, ntiles);
  graph_kernel<<<(G + BM - 1) / BM, 256, 0, stream>>>(pooled, bg1, Wg1t, Wg2, bg2, out, G);
}

// Round 5
// 573.181 us; speedup vs baseline: 1.4114x; 1.3814x over previous
//
#include <hip/hip_runtime.h>
#include <stdint.h>

#define D_IN 128
#define D_H  256
#define BM   64

typedef float f32x4 __attribute__((ext_vector_type(4)));
typedef short s16x8 __attribute__((ext_vector_type(8)));
typedef unsigned int u32x2 __attribute__((ext_vector_type(2)));
typedef unsigned int u32x4 __attribute__((ext_vector_type(4)));

__device__ __forceinline__ unsigned short f2bf(float x) {
  union { float f; uint32_t u; } v; v.f = x;
  uint32_t r = v.u + 0x7fffu + ((v.u >> 16) & 1u);   // RNE
  return (unsigned short)(r >> 16);
}
__device__ __forceinline__ float bf2f(unsigned short u) {
  union { uint32_t u; float f; } v; v.u = (uint32_t)u << 16;
  return v.f;
}
// pack 2 fp32 -> 2 bf16 (RNE), HW instruction when available
__device__ __forceinline__ uint32_t pkbf(float lo, float hi) {
#if __has_builtin(__builtin_amdgcn_cvt_pk_bf16_f32)
  auto r = __builtin_amdgcn_cvt_pk_bf16_f32(lo, hi);
  uint32_t u; __builtin_memcpy(&u, &r, 4); return u;
#else
  return (uint32_t)f2bf(lo) | ((uint32_t)f2bf(hi) << 16);
#endif
}

// ---------------- prep: zero pooled accumulator, cast/transpose weights ----------------
__global__ void prep_kernel(const float* __restrict__ W1, const float* __restrict__ W2,
                            const float* __restrict__ Wg1,
                            float* __restrict__ pooled, unsigned short* __restrict__ W1t,
                            unsigned short* __restrict__ W2t, unsigned short* __restrict__ Wg1t,
                            int pooled_n) {
  int stride = gridDim.x * blockDim.x;
  int tid = blockIdx.x * blockDim.x + threadIdx.x;
  float4 z4 = make_float4(0.f, 0.f, 0.f, 0.f);
  for (int i = tid; i < (pooled_n >> 2); i += stride) ((float4*)pooled)[i] = z4;
  for (int i = tid; i < D_H * D_IN; i += stride) {
    int n = i >> 7, k = i & (D_IN - 1);
    W1t[i] = f2bf(W1[k * D_H + n]);
  }
  for (int i = tid; i < D_H * D_H; i += stride) {
    int n = i >> 8, k = i & (D_H - 1);
    W2t[i]  = f2bf(W2[k * D_H + n]);
    Wg1t[i] = f2bf(Wg1[k * D_H + n]);
  }
}

// ---------------- node MLP + fused segment-sum (one tile per block) ----------------
// R2 structure (known-good: 84 VGPR, no loop, grid = natural pipeline) with LDS
// shrunk 49.7 -> 33 KB: hA (16 KB) aliases buf's upper half (x1 rows 32..63).
// Requires one extra barrier (L1 hA-reads done -> epi1 x1-writes). 4 blocks/CU.
// x1s XOR-swizzled; x2 overwrites x1 after B2; pooling reads own wave's
// feature stripe (same-wave LDS program order, no barrier).
__global__ __launch_bounds__(256, 3)
void node_kernel(const float* __restrict__ h, const int* __restrict__ gids,
                 const float* __restrict__ b1, const float* __restrict__ b2,
                 const unsigned short* __restrict__ W1t, const unsigned short* __restrict__ W2t,
                 float* __restrict__ pooled, int nnodes) {
  __shared__ unsigned short buf[BM * D_H];   // 32 KB: x1/x2 full; hA = buf[8192..16384)
  __shared__ int sgid[BM];
  const int tid  = threadIdx.x;
  const int lane = tid & 63;
  const int wave = tid >> 6;
  const int lr   = lane & 15;   // row-in-16 (A) / col-in-16 (B,C)
  const int q    = lane >> 4;   // quad
  const int row0 = blockIdx.x * BM;
  unsigned short* hA = buf + 8192;

  // ---- preload ALL layer-1 A-frags (64 VGPRs): L2 latency hides behind staging+B0
  s16x8 a[4][4];
  #pragma unroll
  for (int ks = 0; ks < 4; ++ks)
    #pragma unroll
    for (int mt = 0; mt < 4; ++mt)
      a[ks][mt] = *(const s16x8*)&W1t[(wave * 64 + mt * 16 + lr) * D_IN + ks * 32 + q * 8];

  if (tid < BM) {
    int gr = row0 + tid;
    sgid[tid] = (gr < nnodes) ? gids[gr] : -1;   // -1 rows excluded from pooling
  }

  // ---- stage h tile (fp32 -> bf16) into swizzled hA
  #pragma unroll
  for (int i = 0; i < 4; ++i) {
    int gi = tid + i * 256, r = gi >> 4, gc = gi & 15, gr = row0 + r;
    f32x4 v0 = (f32x4){0.f, 0.f, 0.f, 0.f}, v1 = v0;
    if (gr < nnodes) {
      const f32x4* p = (const f32x4*)(h + (size_t)gr * D_IN + gc * 8);
      v0 = __builtin_nontemporal_load(p);       // h is read-once
      v1 = __builtin_nontemporal_load(p + 1);
    }
    u32x4 u;
    u[0] = pkbf(v0[0], v0[1]); u[1] = pkbf(v0[2], v0[3]);
    u[2] = pkbf(v1[0], v1[1]); u[3] = pkbf(v1[2], v1[3]);
    *(u32x4*)&hA[r * D_IN + ((gc ^ (r & 7)) << 3)] = u;
  }
  __syncthreads();   // B0: hA published

  f32x4 acc[4][4];
  #pragma unroll
  for (int mt = 0; mt < 4; ++mt)
    #pragma unroll
    for (int nt = 0; nt < 4; ++nt)
      acc[mt][nt] = (f32x4){0.f, 0.f, 0.f, 0.f};

  // ---- layer 1: x1^T = W1^T(256x128) @ h^T(128x64)
  #pragma unroll
  for (int ks = 0; ks < 4; ++ks) {
    const int kq = ks * 32 + q * 8;
    s16x8 b[4];
    #pragma unroll
    for (int nt = 0; nt < 4; ++nt)
      b[nt] = *(const s16x8*)&hA[(nt * 16 + lr) * D_IN + (((kq >> 3) ^ (lr & 7)) << 3)];
    #pragma unroll
    for (int mt = 0; mt < 4; ++mt)
      #pragma unroll
      for (int nt = 0; nt < 4; ++nt)
        acc[mt][nt] = __builtin_amdgcn_mfma_f32_16x16x32_bf16(a[ks][mt], b[nt], acc[mt][nt], 0, 0, 0);
  }

  // ---- preload W2 half 0 (k=0..127) now: latency spans B1' + epi1 + B1
  #pragma unroll
  for (int ks = 0; ks < 4; ++ks)
    #pragma unroll
    for (int mt = 0; mt < 4; ++mt)
      a[ks][mt] = *(const s16x8*)&W2t[(wave * 64 + mt * 16 + lr) * D_H + ks * 32 + q * 8];

  __syncthreads();   // B1': all hA reads done -> epi1 may overwrite hA region

  // ---- epilogue 1: relu(+b1) -> x1 bf16 swizzled (full 32 KB buf, incl. hA bytes)
  #pragma unroll
  for (int mt = 0; mt < 4; ++mt) {
    int f = wave * 64 + mt * 16 + q * 4;
    float4 bias = *(const float4*)&b1[f];
    #pragma unroll
    for (int nt = 0; nt < 4; ++nt) {
      int nd = nt * 16 + lr;
      u32x2 w;
      w[0] = pkbf(fmaxf(acc[mt][nt][0] + bias.x, 0.f), fmaxf(acc[mt][nt][1] + bias.y, 0.f));
      w[1] = pkbf(fmaxf(acc[mt][nt][2] + bias.z, 0.f), fmaxf(acc[mt][nt][3] + bias.w, 0.f));
      *(u32x2*)&buf[nd * D_H + (((f >> 3) ^ (nd & 7)) << 3) + (f & 7)] = w;
    }
  }
  __syncthreads();   // B1: x1 published

  #pragma unroll
  for (int mt = 0; mt < 4; ++mt)
    #pragma unroll
    for (int nt = 0; nt < 4; ++nt)
      acc[mt][nt] = (f32x4){0.f, 0.f, 0.f, 0.f};

  // ---- layer 2 half 0
  #pragma unroll
  for (int ks = 0; ks < 4; ++ks) {
    const int kq = ks * 32 + q * 8;
    s16x8 b[4];
    #pragma unroll
    for (int nt = 0; nt < 4; ++nt)
      b[nt] = *(const s16x8*)&buf[(nt * 16 + lr) * D_H + (((kq >> 3) ^ (lr & 7)) << 3)];
    #pragma unroll
    for (int mt = 0; mt < 4; ++mt)
      #pragma unroll
      for (int nt = 0; nt < 4; ++nt)
        acc[mt][nt] = __builtin_amdgcn_mfma_f32_16x16x32_bf16(a[ks][mt], b[nt], acc[mt][nt], 0, 0, 0);
  }
  // ---- layer 2 half 1 (reload A into same regs)
  #pragma unroll
  for (int ks = 0; ks < 4; ++ks)
    #pragma unroll
    for (int mt = 0; mt < 4; ++mt)
      a[ks][mt] = *(const s16x8*)&W2t[(wave * 64 + mt * 16 + lr) * D_H + 128 + ks * 32 + q * 8];
  #pragma unroll
  for (int ks = 0; ks < 4; ++ks) {
    const int kq = 128 + ks * 32 + q * 8;
    s16x8 b[4];
    #pragma unroll
    for (int nt = 0; nt < 4; ++nt)
      b[nt] = *(const s16x8*)&buf[(nt * 16 + lr) * D_H + (((kq >> 3) ^ (lr & 7)) << 3)];
    #pragma unroll
    for (int mt = 0; mt < 4; ++mt)
      #pragma unroll
      for (int nt = 0; nt < 4; ++nt)
        acc[mt][nt] = __builtin_amdgcn_mfma_f32_16x16x32_bf16(a[ks][mt], b[nt], acc[mt][nt], 0, 0, 0);
  }
  __syncthreads();   // B2: all x1 reads done -> overwrite with x2

  // ---- epilogue 2: relu(+b2) -> x2 bf16 into buf (same swizzle)
  #pragma unroll
  for (int mt = 0; mt < 4; ++mt) {
    int f = wave * 64 + mt * 16 + q * 4;
    float4 bias = *(const float4*)&b2[f];
    #pragma unroll
    for (int nt = 0; nt < 4; ++nt) {
      int nd = nt * 16 + lr;
      u32x2 w;
      w[0] = pkbf(fmaxf(acc[mt][nt][0] + bias.x, 0.f), fmaxf(acc[mt][nt][1] + bias.y, 0.f));
      w[1] = pkbf(fmaxf(acc[mt][nt][2] + bias.z, 0.f), fmaxf(acc[mt][nt][3] + bias.w, 0.f));
      *(u32x2*)&buf[nd * D_H + (((f >> 3) ^ (nd & 7)) << 3) + (f & 7)] = w;
    }
  }

  // ---- pooling: thread tid reads feature tid = own wave's stripe (same-wave
  //      LDS program order, no barrier). Sorted gids -> run detection.
  {
    const int hi = tid >> 3, lo = tid & 7;
    float racc = 0.f;
    for (int r = 0; r < BM; ++r) {
      int g = sgid[r];                    // wave-uniform
      if (g >= 0) {
        racc += bf2f(buf[r * D_H + ((hi ^ (r & 7)) << 3) + lo]);
        if (r == BM - 1 || sgid[r + 1] != g) {
          atomicAdd(&pooled[g * D_H + tid], racc);
          racc = 0.f;
        }
      }
    }
  }
}

// ---------------- graph MLP: swizzled 32 KB LDS, bf16 y, conflict-free ----------------
__global__ __launch_bounds__(256, 4)
void graph_kernel(const float* __restrict__ pooled, const float* __restrict__ bg1,
                  const unsigned short* __restrict__ Wg1t, const float* __restrict__ Wg2,
                  const float* __restrict__ bg2, float* __restrict__ out, int ngraphs) {
  __shared__ unsigned short pA[BM * D_H];   // 32 KB swizzled; pooled-bf16 then y-bf16
  const int tid  = threadIdx.x;
  const int lane = tid & 63;
  const int wave = tid >> 6;
  const int lr   = lane & 15;
  const int q    = lane >> 4;
  const int g0   = blockIdx.x * BM;

  #pragma unroll
  for (int i = 0; i < 8; ++i) {
    int gi = tid + i * 256, r = gi >> 5, gc = gi & 31;
    int gr = g0 + r;
    f32x4 v0 = (f32x4){0.f, 0.f, 0.f, 0.f}, v1 = v0;
    if (gr < ngraphs) {
      const f32x4* p = (const f32x4*)(pooled + (size_t)gr * D_H + gc * 8);
      v0 = p[0]; v1 = p[1];
    }
    u32x4 u;
    u[0] = pkbf(v0[0], v0[1]); u[1] = pkbf(v0[2], v0[3]);
    u[2] = pkbf(v1[0], v1[1]); u[3] = pkbf(v1[2], v1[3]);
    *(u32x4*)&pA[r * D_H + (((gc & 7) ^ (r & 7)) << 3) + ((gc & 24) << 3)] = u;
  }
  __syncthreads();

  f32x4 acc[4][4];
  #pragma unroll
  for (int mt = 0; mt < 4; ++mt)
    #pragma unroll
    for (int nt = 0; nt < 4; ++nt)
      acc[mt][nt] = (f32x4){0.f, 0.f, 0.f, 0.f};

  #pragma unroll
  for (int ks = 0; ks < 8; ++ks) {
    const int kq = ks * 32 + q * 8;
    s16x8 a[4], b[4];
    #pragma unroll
    for (int mt = 0; mt < 4; ++mt)
      a[mt] = *(const s16x8*)&Wg1t[(wave * 64 + mt * 16 + lr) * D_H + kq];
    #pragma unroll
    for (int nt = 0; nt < 4; ++nt) {
      int row = nt * 16 + lr, gw = kq >> 3;
      b[nt] = *(const s16x8*)&pA[row * D_H + (((gw & 7) ^ (row & 7)) << 3) + ((gw & 24) << 3)];
    }
    #pragma unroll
    for (int mt = 0; mt < 4; ++mt)
      #pragma unroll
      for (int nt = 0; nt < 4; ++nt)
        acc[mt][nt] = __builtin_amdgcn_mfma_f32_16x16x32_bf16(a[mt], b[nt], acc[mt][nt], 0, 0, 0);
  }
  __syncthreads();   // all pA reads done; overwrite with y

  #pragma unroll
  for (int mt = 0; mt < 4; ++mt) {
    int f = wave * 64 + mt * 16 + q * 4;
    float4 bias = *(const float4*)&bg1[f];
    #pragma unroll
    for (int nt = 0; nt < 4; ++nt) {
      int nd = nt * 16 + lr;
      u32x2 w;
      w[0] = pkbf(fmaxf(acc[mt][nt][0] + bias.x, 0.f), fmaxf(acc[mt][nt][1] + bias.y, 0.f));
      w[1] = pkbf(fmaxf(acc[mt][nt][2] + bias.z, 0.f), fmaxf(acc[mt][nt][3] + bias.w, 0.f));
      int gw = f >> 3;
      *(u32x2*)&pA[nd * D_H + (((gw & 7) ^ (nd & 7)) << 3) + ((gw & 24) << 3) + (f & 7)] = w;
    }
  }
  __syncthreads();

  int gloc = tid >> 2;
  int part = tid & 3;
  float p = 0.f;
  #pragma unroll 8
  for (int i = 0; i < 32; ++i) {
    int f2 = part + 4 * i;
    int hw = 2 * f2;
    int gw = hw >> 3;
    uint32_t wv = *(const uint32_t*)&pA[gloc * D_H + (((gw & 7) ^ (gloc & 7)) << 3) +
                                        ((gw & 24) << 3) + (hw & 7)];
    float2 wg = ((const float2*)Wg2)[f2];
    p += bf2f((unsigned short)(wv & 0xffffu)) * wg.x +
         bf2f((unsigned short)(wv >> 16)) * wg.y;
  }
  p += __shfl_xor(p, 1);
  p += __shfl_xor(p, 2);
  if (part == 0 && (g0 + gloc) < ngraphs)
    out[g0 + gloc] = p + bg2[0];
}

extern "C" void kernel_launch(void* const* d_in, const int* in_sizes, int n_in,
                              void* d_out, int out_size, void* d_ws, size_t ws_size,
                              hipStream_t stream) {
  const float* h   = (const float*)d_in[0];
  const int*   gid = (const int*)d_in[1];
  const float* W1  = (const float*)d_in[3];
  const float* b1  = (const float*)d_in[4];
  const float* W2  = (const float*)d_in[5];
  const float* b2  = (const float*)d_in[6];
  const float* Wg1 = (const float*)d_in[7];
  const float* bg1 = (const float*)d_in[8];
  const float* Wg2 = (const float*)d_in[9];
  const float* bg2 = (const float*)d_in[10];
  float* out = (float*)d_out;

  const int N = in_sizes[1];
  const int G = out_size;

  char* ws = (char*)d_ws;
  float* pooled = (float*)ws;                                   // G*256*4 = 20.48 MB
  size_t off = (size_t)G * D_H * sizeof(float);
  unsigned short* W1t  = (unsigned short*)(ws + off); off += (size_t)D_H * D_IN * 2;
  unsigned short* W2t  = (unsigned short*)(ws + off); off += (size_t)D_H * D_H * 2;
  unsigned short* Wg1t = (unsigned short*)(ws + off);

  prep_kernel<<<512, 256, 0, stream>>>(W1, W2, Wg1, pooled, W1t, W2t, Wg1t, G * D_H);
  node_kernel<<<(N + BM - 1) / BM, 256, 0, stream>>>(h, gid, b1, b2, W1t, W2t, pooled, N);
  graph_kernel<<<(G + BM - 1) / BM, 256, 0, stream>>>(pooled, bg1, Wg1t, Wg2, bg2, out, G);
}